// Round 2
// baseline (2254.197 us; speedup 1.0000x reference)
//
#include <hip/hip_runtime.h>

// Grid constants (padded 66^3)
#define GD   66
#define GHW  (66*66)
#define GDHW (66*66*66)
#define CI   32
#define CO   32

// Brick decomposition: 4^3 base cells per brick, 16^3 bricks per batch
#define NBIN 8192              // 2 batches * 16^3 bricks
#define HAL  6                 // halo = brick+2 cells per axis
#define HCELLS (HAL*HAL*HAL)   // 216
#define SBSZ (HCELLS*33 + 8)   // stride-33 swizzled LDS accumulator (dwords)

__device__ __forceinline__ void atomAdd(float* p, float v) {
    unsafeAtomicAdd(p, v);   // native global_atomic_add_f32
}

// ---------------- sort phase ----------------

__global__ __launch_bounds__(256) void binhist(
    const float* __restrict__ pos, int* __restrict__ counts, int BN, int N)
{
    int g = blockIdx.x * 256 + threadIdx.x;
    if (g >= BN) return;
    int bx = (int)(pos[3*g+0] * 64.f);
    int by = (int)(pos[3*g+1] * 64.f);
    int bz = (int)(pos[3*g+2] * 64.f);
    int bin = ((g >= N) << 12) | ((bx >> 2) << 8) | ((by >> 2) << 4) | (bz >> 2);
    atomicAdd(counts + bin, 1);
}

__global__ __launch_bounds__(1024) void binscan(
    const int* __restrict__ counts, int* __restrict__ offs, int* __restrict__ cursor)
{
    __shared__ int s[1024];
    const int t = threadIdx.x;
    int loc[8]; int sum = 0;
    #pragma unroll
    for (int j = 0; j < 8; ++j) { loc[j] = sum; sum += counts[t*8 + j]; }
    s[t] = sum; __syncthreads();
    for (int off = 1; off < 1024; off <<= 1) {
        int v = (t >= off) ? s[t - off] : 0;
        __syncthreads();
        s[t] += v;
        __syncthreads();
    }
    int base = (t > 0) ? s[t-1] : 0;
    #pragma unroll
    for (int j = 0; j < 8; ++j) { offs[t*8+j] = base + loc[j]; cursor[t*8+j] = base + loc[j]; }
    if (t == 1023) offs[NBIN] = s[1023];
}

__global__ __launch_bounds__(256) void binscat(
    const float* __restrict__ pos, int* __restrict__ cursor,
    int* __restrict__ sidx, int BN, int N)
{
    int g = blockIdx.x * 256 + threadIdx.x;
    if (g >= BN) return;
    int bx = (int)(pos[3*g+0] * 64.f);
    int by = (int)(pos[3*g+1] * 64.f);
    int bz = (int)(pos[3*g+2] * 64.f);
    int bin = ((g >= N) << 12) | ((bx >> 2) << 8) | ((by >> 2) << 4) | (bz >> 2);
    int dst = atomicAdd(cursor + bin, 1);
    sidx[dst] = g;
}

// ---------------- main phase: one wave per brick, lane = particle ----------------

__global__ __launch_bounds__(64) void p2g_brick(
    const float* __restrict__ x, const float* __restrict__ pos,
    const float* __restrict__ kern, const float* __restrict__ bias,
    const int* __restrict__ sidx, const int* __restrict__ offs,
    float* __restrict__ ws)
{
    __shared__ float sb[SBSZ];
    const int bid = blockIdx.x;
    const int p0 = offs[bid], p1 = offs[bid + 1];
    if (p0 == p1) return;                     // empty brick: contributes nothing
    const int batch = bid >> 12;
    const int br  = bid & 4095;
    const int gx0 = ((br >> 8) & 15) * 4;
    const int gy0 = ((br >> 4) & 15) * 4;
    const int gz0 = (br & 15) * 4;

    for (int e = threadIdx.x; e < SBSZ; e += 64) sb[e] = 0.f;
    __syncthreads();

    for (int p = p0 + (int)threadIdx.x; p < p1; p += 64) {
        const int g = sidx[p];
        const float px = pos[3*g+0]*64.f, py = pos[3*g+1]*64.f, pz = pos[3*g+2]*64.f;
        const int bx = (int)px, by = (int)py, bz = (int)pz;
        const float fx = px - bx - 0.5f, fy = py - by - 0.5f, fz = pz - bz - 0.5f;
        const float wx0 = 0.5f*(0.5f-fx)*(0.5f-fx), wx1 = 0.75f-fx*fx, wx2 = 0.5f*(0.5f+fx)*(0.5f+fx);
        const float wy0 = 0.5f*(0.5f-fy)*(0.5f-fy), wy1 = 0.75f-fy*fy, wy2 = 0.5f*(0.5f+fy)*(0.5f+fy);
        const float wz0 = 0.5f*(0.5f-fz)*(0.5f-fz), wz1 = 0.75f-fz*fz, wz2 = 0.5f*(0.5f+fz)*(0.5f+fz);
        const int lx = bx - gx0, ly = by - gy0, lz = bz - gz0;   // in [0,4)

        // this lane's particle feature row, register resident
        float xr[32];
        const float4* xp = (const float4*)(x + (size_t)g * CI);
        #pragma unroll
        for (int i = 0; i < 8; ++i) {
            float4 v = xp[i];
            xr[4*i+0]=v.x; xr[4*i+1]=v.y; xr[4*i+2]=v.z; xr[4*i+3]=v.w;
        }

        #pragma unroll 1
        for (int o = 0; o < 27; ++o) {        // uniform loop; K loads scalarize
            const int oi = o / 9, oj = (o / 3) % 3, ok = o % 3;
            const float* kb = kern + (size_t)o * 1024;
            float acc[32];
            #pragma unroll
            for (int c = 0; c < 32; ++c) acc[c] = bias[c];
            #pragma unroll
            for (int ci = 0; ci < 32; ++ci) {
                const float xv = xr[ci];
                #pragma unroll
                for (int c = 0; c < 32; ++c)
                    acc[c] = fmaf(kb[ci*32 + c], xv, acc[c]);  // K from SGPR operand
            }
            const float w = (oi==0 ? wx0 : oi==1 ? wx1 : wx2)
                          * (oj==0 ? wy0 : oj==1 ? wy1 : wy2)
                          * (ok==0 ? wz0 : ok==1 ? wz1 : wz2);
            float* sp = sb + ((lx+oi)*36 + (ly+oj)*6 + (lz+ok)) * 33; // stride-33: banks spread
            #pragma unroll
            for (int c = 0; c < 32; ++c)
                atomicAdd(sp + c, w * acc[c]);                 // ds_add_f32, offset:c*4
        }
    }
    __syncthreads();

    // flush halo brick to ws[b][cell][co] with coalesced global atomics
    for (int e = threadIdx.x; e < HCELLS * 32; e += 64) {
        const int cell = e >> 5, c = e & 31;
        const float v = sb[cell*33 + c];
        if (v != 0.f) {
            const int cz = cell % 6, cy = (cell / 6) % 6, cx = cell / 36;
            atomAdd(ws + ((size_t)batch*GDHW + (size_t)(gx0+cx)*GHW
                          + (size_t)(gy0+cy)*GD + (gz0+cz)) * 32 + c, v);
        }
    }
}

// Transpose ws[b][cell][co] -> out[b][co][cell], tiled 32x32 through LDS.
__global__ __launch_bounds__(256) void transp_kernel(
    const float* __restrict__ ws, float* __restrict__ out)
{
    __shared__ float tile[32][33];
    const int b     = blockIdx.y;
    const int cell0 = blockIdx.x * 32;
    const int n     = min(32, GDHW - cell0);

    const float* src = ws + ((size_t)b*GDHW + cell0)*32;
    for (int e = threadIdx.x; e < n*32; e += 256)
        tile[e>>5][e&31] = src[e];
    __syncthreads();
    for (int e = threadIdx.x; e < 32*32; e += 256) {
        int c  = e >> 5;
        int cl = e & 31;
        if (cl < n)
            out[((size_t)(b*32 + c))*GDHW + cell0 + cl] = tile[cl][c];
    }
}

// ---------------- fallback (round-1 kernel), used only if ws too small ----------------

template<bool CELLCO>
__global__ __launch_bounds__(256) void p2g_kernel(
    const float* __restrict__ x, const float* __restrict__ pos,
    const float* __restrict__ kern, const float* __restrict__ bias,
    float* __restrict__ dst, int N, int nPairs)
{
    __shared__ float kl[9*32*32];
    const int co   = threadIdx.x & 31;
    const int half = threadIdx.x >> 5;
    const float bco = bias[co];
    const int halvesTotal = gridDim.x * 8;

    for (int oi = 0; oi < 3; ++oi) {
        __syncthreads();
        for (int i = threadIdx.x; i < 9*32*32; i += 256)
            kl[i] = kern[oi*(9*32*32) + i];
        __syncthreads();

        for (int pp = blockIdx.x*8 + half; pp < nPairs; pp += halvesTotal) {
            const int g0 = pp*2;
            float xr[2][32];
            #pragma unroll
            for (int p = 0; p < 2; ++p) {
                const float4* xp = (const float4*)(x + (size_t)(g0+p)*CI);
                #pragma unroll
                for (int i = 0; i < 8; ++i) {
                    float4 v = xp[i];
                    xr[p][4*i+0]=v.x; xr[p][4*i+1]=v.y; xr[p][4*i+2]=v.z; xr[p][4*i+3]=v.w;
                }
            }
            float wxo[2], wy[2][3], wz[2][3];
            int cb[2], bsel[2];
            #pragma unroll
            for (int p = 0; p < 2; ++p) {
                const int gp = g0 + p;
                float px = pos[gp*3+0]*64.f, py = pos[gp*3+1]*64.f, pz = pos[gp*3+2]*64.f;
                int bx = (int)px, by = (int)py, bz = (int)pz;
                float fx = px - bx - 0.5f, fy = py - by - 0.5f, fz = pz - bz - 0.5f;
                float a0 = 0.5f*(0.5f-fx)*(0.5f-fx);
                float a1 = 0.75f - fx*fx;
                float a2 = 0.5f*(0.5f+fx)*(0.5f+fx);
                wxo[p] = (oi==0) ? a0 : ((oi==1) ? a1 : a2);
                wy[p][0]=0.5f*(0.5f-fy)*(0.5f-fy); wy[p][1]=0.75f-fy*fy; wy[p][2]=0.5f*(0.5f+fy)*(0.5f+fy);
                wz[p][0]=0.5f*(0.5f-fz)*(0.5f-fz); wz[p][1]=0.75f-fz*fz; wz[p][2]=0.5f*(0.5f+fz)*(0.5f+fz);
                cb[p]   = (bx+oi)*GHW + by*GD + bz;
                bsel[p] = (gp >= N) ? 1 : 0;
            }
            #pragma unroll
            for (int oj = 0; oj < 3; ++oj) {
                #pragma unroll
                for (int ok = 0; ok < 3; ++ok) {
                    const float* kc = kl + (oj*3+ok)*1024;
                    float y0 = bco, y1 = bco;
                    #pragma unroll
                    for (int ci = 0; ci < 32; ++ci) {
                        float kv = kc[ci*32 + co];
                        y0 += xr[0][ci]*kv;
                        y1 += xr[1][ci]*kv;
                    }
                    {
                        int cell = cb[0] + oj*GD + ok;
                        float w  = wxo[0]*wy[0][oj]*wz[0][ok];
                        size_t a = CELLCO ? (((size_t)bsel[0]*GDHW + cell)*32 + (size_t)co)
                                          : (((size_t)(bsel[0]*32 + co))*GDHW + (size_t)cell);
                        atomAdd(dst + a, w*y0);
                    }
                    {
                        int cell = cb[1] + oj*GD + ok;
                        float w  = wxo[1]*wy[1][oj]*wz[1][ok];
                        size_t a = CELLCO ? (((size_t)bsel[1]*GDHW + cell)*32 + (size_t)co)
                                          : (((size_t)(bsel[1]*32 + co))*GDHW + (size_t)cell);
                        atomAdd(dst + a, w*y1);
                    }
                }
            }
        }
    }
}

extern "C" void kernel_launch(void* const* d_in, const int* in_sizes, int n_in,
                              void* d_out, int out_size, void* d_ws, size_t ws_size,
                              hipStream_t stream) {
    const float* x    = (const float*)d_in[0];
    const float* pos  = (const float*)d_in[1];
    const float* kern = (const float*)d_in[2];
    const float* bias = (const float*)d_in[3];
    float* out = (float*)d_out;

    const int N  = in_sizes[0] / (2*CI);
    const int BN = 2*N;

    const size_t GRIDB   = (size_t)2 * GDHW * CO * sizeof(float);  // 73,598,976
    const size_t oCounts = GRIDB;
    const size_t oOffs   = oCounts + 32768;          // 8192 ints
    const size_t oCur    = oOffs   + 33024;          // 8193 ints (padded)
    const size_t oIdx    = oCur    + 32768;          // 8192 ints
    const size_t need    = oIdx + (size_t)BN * 4;

    if (ws_size >= need) {
        char*  w8     = (char*)d_ws;
        float* wsg    = (float*)w8;
        int*   counts = (int*)(w8 + oCounts);
        int*   offs   = (int*)(w8 + oOffs);
        int*   cursor = (int*)(w8 + oCur);
        int*   sidxb  = (int*)(w8 + oIdx);

        hipMemsetAsync(counts, 0, 32768, stream);
        hipMemsetAsync(wsg, 0, GRIDB, stream);
        binhist<<<dim3((BN + 255)/256), dim3(256), 0, stream>>>(pos, counts, BN, N);
        binscan<<<dim3(1), dim3(1024), 0, stream>>>(counts, offs, cursor);
        binscat<<<dim3((BN + 255)/256), dim3(256), 0, stream>>>(pos, cursor, sidxb, BN, N);
        p2g_brick<<<dim3(NBIN), dim3(64), 0, stream>>>(x, pos, kern, bias, sidxb, offs, wsg);
        transp_kernel<<<dim3((GDHW + 31)/32, 2), dim3(256), 0, stream>>>(wsg, out);
    } else if (ws_size >= GRIDB) {
        float* wsg = (float*)d_ws;
        hipMemsetAsync(wsg, 0, GRIDB, stream);
        p2g_kernel<true><<<dim3(2048), dim3(256), 0, stream>>>(x, pos, kern, bias, wsg, N, (BN+1)/2);
        transp_kernel<<<dim3((GDHW + 31)/32, 2), dim3(256), 0, stream>>>(wsg, out);
    } else {
        hipMemsetAsync(out, 0, (size_t)out_size * sizeof(float), stream);
        p2g_kernel<false><<<dim3(2048), dim3(256), 0, stream>>>(x, pos, kern, bias, out, N, (BN+1)/2);
    }
}